// Round 1
// baseline (818.618 us; speedup 1.0000x reference)
//
#include <hip/hip_runtime.h>

// GNN_44306882625625: 2-layer SAGEConv + node-sum readout, fp32.
// Layer-2 is collapsed algebraically: out = S_hw @ W2l^T + N*b2 + S_h @ W2r^T
// with S_h = sum_n h[n], S_hw = sum_n wsum[n]*h[n],
// wsum[n] = sum_{edges e with src=n} 1/max(cnt[dst_e],1).

constexpr int N = 50000;   // nodes
constexpr int F = 64;      // in feat
constexpr int H = 128;     // hidden
constexpr int O = 10;      // out
constexpr int E = 800000;  // edges

// workspace layout (floats)
constexpr int AGG_OFF  = 0;              // N*F   : agg1[dst] += x[src]
constexpr int CNT_OFF  = N * F;          // N     : in-degree (float)
constexpr int WSO_OFF  = CNT_OFF + N;    // N     : wsum[src] += 1/max(cnt[dst],1)
constexpr int SH_OFF   = WSO_OFF + N;    // H     : sum_n h[n]
constexpr int SHW_OFF  = SH_OFF + H;     // H     : sum_n wsum[n]*h[n]
constexpr int WS_TOTAL = SHW_OFF + H;    // 3,300,256 floats = 13.2 MB

__global__ __launch_bounds__(256) void k_zero(float* __restrict__ ws) {
  int tid = blockIdx.x * blockDim.x + threadIdx.x;
  int stride = gridDim.x * blockDim.x;
  float4* p = reinterpret_cast<float4*>(ws);
  constexpr int n4 = WS_TOTAL / 4;  // divisible by 4
  for (int i = tid; i < n4; i += stride)
    p[i] = make_float4(0.f, 0.f, 0.f, 0.f);
}

// One wave per 64-edge chunk: lanes cooperatively read 64 (src,dst) pairs
// coalesced, then for each edge all 64 lanes scatter-add one 256B row of x
// into agg1[dst] (coalesced atomics). Lane also counts its own edge's dst.
__global__ __launch_bounds__(256) void k_edge_agg(
    const float* __restrict__ x, const int* __restrict__ ei,
    float* __restrict__ agg1, float* __restrict__ cntf) {
  const int* __restrict__ src = ei;
  const int* __restrict__ dst = ei + E;
  const int lane = threadIdx.x & 63;
  const int gwave = (blockIdx.x * blockDim.x + threadIdx.x) >> 6;
  const int nwaves = (gridDim.x * blockDim.x) >> 6;
  for (int base = gwave * 64; base < E; base += nwaves * 64) {
    // E % 64 == 0, so no tail
    const int s = src[base + lane];
    const int d = dst[base + lane];
    atomicAdd(&cntf[d], 1.0f);
    #pragma unroll 4
    for (int i = 0; i < 64; ++i) {
      const int si = __shfl(s, i, 64);
      const int di = __shfl(d, i, 64);
      atomicAdd(&agg1[di * F + lane], x[si * F + lane]);
    }
  }
}

// wsum[src] += 1/max(cnt[dst],1) — one thread per edge.
__global__ __launch_bounds__(256) void k_edge_ws(
    const int* __restrict__ ei, const float* __restrict__ cntf,
    float* __restrict__ wsum) {
  const int* __restrict__ src = ei;
  const int* __restrict__ dst = ei + E;
  int tid = blockIdx.x * blockDim.x + threadIdx.x;
  int stride = gridDim.x * blockDim.x;
  for (int e = tid; e < E; e += stride) {
    float c = cntf[dst[e]];
    atomicAdd(&wsum[src[e]], 1.0f / fmaxf(c, 1.0f));
  }
}

// Per-node layer 1 + fused global reductions. Lane = node. Weights are
// wave-uniform -> s_load (SGPR FMA operand); a[]/x[] live in VGPRs
// (fully-unrolled static indexing only). h is never stored: per-j wave
// shfl-reduce -> 2 atomics per wave per j.
__global__ __launch_bounds__(256) void k_node(
    const float* __restrict__ x, const float* __restrict__ agg1,
    const float* __restrict__ cntf, const float* __restrict__ wsum,
    const float* __restrict__ W1l, const float* __restrict__ b1,
    const float* __restrict__ W1r,
    float* __restrict__ S_h, float* __restrict__ S_hw) {
  const int lane = threadIdx.x & 63;
  const int gwave = (blockIdx.x * blockDim.x + threadIdx.x) >> 6;
  const int nwaves = (gridDim.x * blockDim.x) >> 6;
  for (int base = gwave * 64; base < N; base += nwaves * 64) {
    const int n = base + lane;
    const bool valid = (n < N);
    const int nn = valid ? n : 0;

    float winv = valid ? (1.0f / fmaxf(cntf[nn], 1.0f)) : 0.0f;
    const float wsn = valid ? wsum[nn] : 0.0f;

    float a[F], xl[F];
    const float4* ap = reinterpret_cast<const float4*>(agg1 + (size_t)nn * F);
    const float4* xp = reinterpret_cast<const float4*>(x + (size_t)nn * F);
    #pragma unroll
    for (int i = 0; i < F / 4; ++i) {
      float4 t = ap[i];
      a[4 * i] = t.x * winv; a[4 * i + 1] = t.y * winv;
      a[4 * i + 2] = t.z * winv; a[4 * i + 3] = t.w * winv;
      float4 u = xp[i];
      xl[4 * i] = u.x; xl[4 * i + 1] = u.y;
      xl[4 * i + 2] = u.z; xl[4 * i + 3] = u.w;
    }
    if (!valid) {
      #pragma unroll
      for (int i = 0; i < F; ++i) { a[i] = 0.f; xl[i] = 0.f; }
    }

    for (int j = 0; j < H; ++j) {
      const float* __restrict__ wl = W1l + j * F;  // uniform -> s_load
      const float* __restrict__ wr = W1r + j * F;
      float z0 = 0.f, z1 = 0.f, z2 = 0.f, z3 = 0.f;  // 4 indep FMA chains
      #pragma unroll
      for (int k = 0; k < F; k += 2) {
        z0 += wl[k] * a[k];
        z1 += wl[k + 1] * a[k + 1];
        z2 += wr[k] * xl[k];
        z3 += wr[k + 1] * xl[k + 1];
      }
      float z = (z0 + z1) + (z2 + z3) + b1[j];
      float h = valid ? fmaxf(z, 0.0f) : 0.0f;
      float hw = wsn * h;
      #pragma unroll
      for (int m = 1; m < 64; m <<= 1) {
        h += __shfl_xor(h, m, 64);
        hw += __shfl_xor(hw, m, 64);
      }
      if (lane == 0) {
        atomicAdd(&S_h[j], h);
        atomicAdd(&S_hw[j], hw);
      }
    }
  }
}

__global__ __launch_bounds__(64) void k_final(
    const float* __restrict__ S_h, const float* __restrict__ S_hw,
    const float* __restrict__ W2l, const float* __restrict__ b2,
    const float* __restrict__ W2r, float* __restrict__ out) {
  const int j = threadIdx.x;
  if (j < O) {
    float acc = (float)N * b2[j];
    #pragma unroll 8
    for (int k = 0; k < H; ++k)
      acc += S_hw[k] * W2l[j * H + k] + S_h[k] * W2r[j * H + k];
    out[j] = acc;
  }
}

extern "C" void kernel_launch(void* const* d_in, const int* in_sizes, int n_in,
                              void* d_out, int out_size, void* d_ws, size_t ws_size,
                              hipStream_t stream) {
  const float* x   = (const float*)d_in[0];
  const int*   ei  = (const int*)d_in[1];
  const float* W1l = (const float*)d_in[2];
  const float* b1  = (const float*)d_in[3];
  const float* W1r = (const float*)d_in[4];
  const float* W2l = (const float*)d_in[5];
  const float* b2  = (const float*)d_in[6];
  const float* W2r = (const float*)d_in[7];
  float* out = (float*)d_out;
  float* ws  = (float*)d_ws;

  float* agg1 = ws + AGG_OFF;
  float* cntf = ws + CNT_OFF;
  float* wsum = ws + WSO_OFF;
  float* S_h  = ws + SH_OFF;
  float* S_hw = ws + SHW_OFF;

  // ws must be re-zeroed every call (harness doesn't re-poison between replays)
  hipLaunchKernelGGL(k_zero, dim3(2048), dim3(256), 0, stream, ws);
  // 12500 64-edge chunks -> exactly 12500 waves
  hipLaunchKernelGGL(k_edge_agg, dim3(3125), dim3(256), 0, stream, x, ei, agg1, cntf);
  hipLaunchKernelGGL(k_edge_ws, dim3(1024), dim3(256), 0, stream, ei, cntf, wsum);
  // 782 64-node chunks -> 784 waves (196 blocks x 4 waves)
  hipLaunchKernelGGL(k_node, dim3(196), dim3(256), 0, stream,
                     x, agg1, cntf, wsum, W1l, b1, W1r, S_h, S_hw);
  hipLaunchKernelGGL(k_final, dim3(1), dim3(64), 0, stream,
                     S_h, S_hw, W2l, b2, W2r, out);
}

// Round 2
// 355.942 us; speedup vs baseline: 2.2999x; 2.2999x over previous
//
#include <hip/hip_runtime.h>

// GNN_44306882625625: 2-layer SAGEConv + node-sum readout, fp32.
// Layer-2 collapsed algebraically: out = S_hw @ W2l^T + N*b2 + S_h @ W2r^T
// with S_h = sum_n h[n], S_hw = sum_n wsum[n]*h[n],
// wsum[n] = sum_{edges e with src=n} 1/max(cnt[dst_e],1).

constexpr int N = 50000;   // nodes
constexpr int F = 64;      // in feat
constexpr int H = 128;     // hidden
constexpr int O = 10;      // out
constexpr int E = 800000;  // edges

constexpr int NWG_NODE = 1024;  // workgroups for k_node (128 thr = 2 waves each)

// workspace layout (floats)
constexpr int AGG_OFF  = 0;              // N*F   : agg1[dst] += x[src]
constexpr int CNT_OFF  = N * F;          // N     : in-degree (float)
constexpr int WSO_OFF  = CNT_OFF + N;    // N     : wsum[src] += 1/max(cnt[dst],1)
constexpr int SH_OFF   = WSO_OFF + N;    // H     : sum_n h[n]
constexpr int SHW_OFF  = SH_OFF + H;     // H     : sum_n wsum[n]*h[n]
constexpr int WS_TOTAL = SHW_OFF + H;    // 3,300,256 floats = 13.2 MB

__global__ __launch_bounds__(256) void k_zero(float* __restrict__ ws) {
  int tid = blockIdx.x * blockDim.x + threadIdx.x;
  int stride = gridDim.x * blockDim.x;
  float4* p = reinterpret_cast<float4*>(ws);
  constexpr int n4 = WS_TOTAL / 4;  // divisible by 4
  for (int i = tid; i < n4; i += stride)
    p[i] = make_float4(0.f, 0.f, 0.f, 0.f);
}

// One wave per 64-edge chunk: lanes cooperatively read 64 (src,dst) pairs
// coalesced, then for each edge all 64 lanes scatter-add one 256B row of x
// into agg1[dst] (coalesced atomics). Lane also counts its own edge's dst.
__global__ __launch_bounds__(256) void k_edge_agg(
    const float* __restrict__ x, const int* __restrict__ ei,
    float* __restrict__ agg1, float* __restrict__ cntf) {
  const int* __restrict__ src = ei;
  const int* __restrict__ dst = ei + E;
  const int lane = threadIdx.x & 63;
  const int gwave = (blockIdx.x * blockDim.x + threadIdx.x) >> 6;
  const int nwaves = (gridDim.x * blockDim.x) >> 6;
  for (int base = gwave * 64; base < E; base += nwaves * 64) {
    // E % 64 == 0, so no tail
    const int s = src[base + lane];
    const int d = dst[base + lane];
    atomicAdd(&cntf[d], 1.0f);
    #pragma unroll 4
    for (int i = 0; i < 64; ++i) {
      const int si = __shfl(s, i, 64);
      const int di = __shfl(d, i, 64);
      atomicAdd(&agg1[di * F + lane], x[si * F + lane]);
    }
  }
}

// wsum[src] += 1/max(cnt[dst],1) — one thread per edge.
__global__ __launch_bounds__(256) void k_edge_ws(
    const int* __restrict__ ei, const float* __restrict__ cntf,
    float* __restrict__ wsum) {
  const int* __restrict__ src = ei;
  const int* __restrict__ dst = ei + E;
  int tid = blockIdx.x * blockDim.x + threadIdx.x;
  int stride = gridDim.x * blockDim.x;
  for (int e = tid; e < E; e += stride) {
    float c = cntf[dst[e]];
    atomicAdd(&wsum[src[e]], 1.0f / fmaxf(c, 1.0f));
  }
}

// Transposed layer-1: lane = hidden unit j (2 waves cover j=0..127).
// Weight rows live in VGPRs (static indexing only -> no scratch). Node loop
// broadcasts features as wave-uniform loads; winv applied AFTER the dot
// (linearity). S_h/S_hw accumulate in 2 registers per lane; one coalesced
// 64-lane atomic per array per wave at the end.
__global__ __launch_bounds__(128) void k_node(
    const float* __restrict__ x, const float* __restrict__ agg1,
    const float* __restrict__ cntf, const float* __restrict__ wsum,
    const float* __restrict__ W1l, const float* __restrict__ b1,
    const float* __restrict__ W1r,
    float* __restrict__ S_h, float* __restrict__ S_hw) {
  const int lane = threadIdx.x & 63;
  const int jhalf = threadIdx.x >> 6;  // 0 or 1
  const int j = jhalf * 64 + lane;

  // per-lane weight rows -> 128 VGPRs, statically indexed
  float wl[F], wr[F];
  const float4* wlp = reinterpret_cast<const float4*>(W1l + j * F);  // 256B aligned
  const float4* wrp = reinterpret_cast<const float4*>(W1r + j * F);
  #pragma unroll
  for (int i = 0; i < F / 4; ++i) {
    float4 t = wlp[i];
    wl[4 * i] = t.x; wl[4 * i + 1] = t.y; wl[4 * i + 2] = t.z; wl[4 * i + 3] = t.w;
    float4 u = wrp[i];
    wr[4 * i] = u.x; wr[4 * i + 1] = u.y; wr[4 * i + 2] = u.z; wr[4 * i + 3] = u.w;
  }
  const float b1j = b1[j];

  float accS = 0.f, accW = 0.f;
  const int w = blockIdx.x;
  const int n0 = (int)(((long long)w * N) / NWG_NODE);
  const int n1 = (int)(((long long)(w + 1) * N) / NWG_NODE);

  for (int n = n0; n < n1; ++n) {
    const float4* __restrict__ ar = reinterpret_cast<const float4*>(agg1 + (size_t)n * F);
    const float4* __restrict__ xr = reinterpret_cast<const float4*>(x + (size_t)n * F);
    float zl0 = 0.f, zl1 = 0.f, zr0 = 0.f, zr1 = 0.f;  // 4 indep FMA chains
    #pragma unroll
    for (int i = 0; i < F / 4; ++i) {
      float4 av = ar[i];  // wave-uniform address -> broadcast load
      float4 xv = xr[i];
      zl0 = fmaf(wl[4 * i + 0], av.x, zl0);
      zl1 = fmaf(wl[4 * i + 1], av.y, zl1);
      zl0 = fmaf(wl[4 * i + 2], av.z, zl0);
      zl1 = fmaf(wl[4 * i + 3], av.w, zl1);
      zr0 = fmaf(wr[4 * i + 0], xv.x, zr0);
      zr1 = fmaf(wr[4 * i + 1], xv.y, zr1);
      zr0 = fmaf(wr[4 * i + 2], xv.z, zr0);
      zr1 = fmaf(wr[4 * i + 3], xv.w, zr1);
    }
    const float winv = 1.0f / fmaxf(cntf[n], 1.0f);
    const float h = fmaxf((zl0 + zl1) * winv + b1j + (zr0 + zr1), 0.0f);
    accS += h;
    accW += wsum[n] * h;
  }

  atomicAdd(&S_h[j], accS);
  atomicAdd(&S_hw[j], accW);
}

__global__ __launch_bounds__(64) void k_final(
    const float* __restrict__ S_h, const float* __restrict__ S_hw,
    const float* __restrict__ W2l, const float* __restrict__ b2,
    const float* __restrict__ W2r, float* __restrict__ out) {
  const int j = threadIdx.x;
  if (j < O) {
    float acc = (float)N * b2[j];
    #pragma unroll 8
    for (int k = 0; k < H; ++k)
      acc += S_hw[k] * W2l[j * H + k] + S_h[k] * W2r[j * H + k];
    out[j] = acc;
  }
}

extern "C" void kernel_launch(void* const* d_in, const int* in_sizes, int n_in,
                              void* d_out, int out_size, void* d_ws, size_t ws_size,
                              hipStream_t stream) {
  const float* x   = (const float*)d_in[0];
  const int*   ei  = (const int*)d_in[1];
  const float* W1l = (const float*)d_in[2];
  const float* b1  = (const float*)d_in[3];
  const float* W1r = (const float*)d_in[4];
  const float* W2l = (const float*)d_in[5];
  const float* b2  = (const float*)d_in[6];
  const float* W2r = (const float*)d_in[7];
  float* out = (float*)d_out;
  float* ws  = (float*)d_ws;

  float* agg1 = ws + AGG_OFF;
  float* cntf = ws + CNT_OFF;
  float* wsum = ws + WSO_OFF;
  float* S_h  = ws + SH_OFF;
  float* S_hw = ws + SHW_OFF;

  // ws must be re-zeroed every call (harness doesn't re-poison between replays)
  hipLaunchKernelGGL(k_zero, dim3(2048), dim3(256), 0, stream, ws);
  hipLaunchKernelGGL(k_edge_agg, dim3(3125), dim3(256), 0, stream, x, ei, agg1, cntf);
  hipLaunchKernelGGL(k_edge_ws, dim3(1024), dim3(256), 0, stream, ei, cntf, wsum);
  hipLaunchKernelGGL(k_node, dim3(NWG_NODE), dim3(128), 0, stream,
                     x, agg1, cntf, wsum, W1l, b1, W1r, S_h, S_hw);
  hipLaunchKernelGGL(k_final, dim3(1), dim3(64), 0, stream,
                     S_h, S_hw, W2l, b2, W2r, out);
}

// Round 3
// 274.579 us; speedup vs baseline: 2.9814x; 1.2963x over previous
//
#include <hip/hip_runtime.h>

// GNN_44306882625625: 2-layer SAGEConv + node-sum readout, fp32.
// Layer-2 collapsed algebraically: out = S_hw @ W2l^T + N*b2 + S_h @ W2r^T
// with S_h = sum_n h[n], S_hw = sum_n wsum[n]*h[n],
// wsum[n] = sum_{edges e: src=n} 1/max(cnt[dst_e],1).
// Layer-1 aggregation via CSR build (hist/scan/scatter) + per-node gather:
// zero feature-plane atomics, x stays L2/L3-resident.

constexpr int N = 50000;   // nodes
constexpr int F = 64;      // in feat
constexpr int H = 128;     // hidden
constexpr int O = 10;      // out
constexpr int E = 800000;  // edges

constexpr int SCAN_B = 256;
constexpr int NBLK_SCAN = (N + SCAN_B - 1) / SCAN_B;  // 196

// workspace layout (4-byte element offsets)
constexpr int AGG_OFF  = 0;                 // N*F floats : mean1
constexpr int CNT_OFF  = AGG_OFF + N * F;   // N ints     : in-degree
constexpr int WSUM_OFF = CNT_OFF + N;       // N floats   : wsum
constexpr int WOFF_OFF = WSUM_OFF + N;      // N ints     : CSR row starts
constexpr int WPOS_OFF = WOFF_OFF + N;      // N ints     : scatter cursors
constexpr int ADJ_OFF  = WPOS_OFF + N;      // E ints     : CSR src ids
constexpr int BSUM_OFF = ADJ_OFF + E;       // 256 ints   : scan block sums
constexpr int BSC_OFF  = BSUM_OFF + 256;    // 256 ints   : scanned block sums
constexpr int SH_OFF   = BSC_OFF + 256;     // H floats
constexpr int SHW_OFF  = SH_OFF + H;        // H floats
constexpr int WS_TOTAL = SHW_OFF + H;       // ~4.2M elems = 16.8 MB

// zero cnt+wsum (contiguous 2N) and S_h+S_hw (contiguous 2H)
__global__ __launch_bounds__(256) void k_zero(float* __restrict__ ws) {
  int tid = blockIdx.x * blockDim.x + threadIdx.x;
  if (tid < 2 * N) ws[CNT_OFF + tid] = 0.0f;  // cnt (int 0 == float 0 bits)
  if (tid < 2 * H) ws[SH_OFF + tid] = 0.0f;
}

__global__ __launch_bounds__(256) void k_hist(
    const int* __restrict__ ei, int* __restrict__ cnt) {
  int e = blockIdx.x * blockDim.x + threadIdx.x;
  if (e < E) atomicAdd(&cnt[ei[E + e]], 1);
}

// block-level exclusive scan of cnt -> woff (partial), block totals -> bsum
__global__ __launch_bounds__(SCAN_B) void k_scan1(
    const int* __restrict__ cnt, int* __restrict__ woff, int* __restrict__ bsum) {
  __shared__ int s[SCAN_B];
  const int t = threadIdx.x;
  const int i = blockIdx.x * SCAN_B + t;
  const int v = (i < N) ? cnt[i] : 0;
  s[t] = v;
  __syncthreads();
  for (int off = 1; off < SCAN_B; off <<= 1) {
    int u = (t >= off) ? s[t - off] : 0;
    __syncthreads();
    s[t] += u;
    __syncthreads();
  }
  if (i < N) woff[i] = s[t] - v;            // exclusive within block
  if (t == SCAN_B - 1) bsum[blockIdx.x] = s[t];
}

// single-block exclusive scan of bsum -> bscan
__global__ __launch_bounds__(SCAN_B) void k_scan2(
    const int* __restrict__ bsum, int* __restrict__ bscan) {
  __shared__ int s[SCAN_B];
  const int t = threadIdx.x;
  const int v = (t < NBLK_SCAN) ? bsum[t] : 0;
  s[t] = v;
  __syncthreads();
  for (int off = 1; off < SCAN_B; off <<= 1) {
    int u = (t >= off) ? s[t - off] : 0;
    __syncthreads();
    s[t] += u;
    __syncthreads();
  }
  if (t < NBLK_SCAN) bscan[t] = s[t] - v;
}

// add block offsets; init scatter cursors
__global__ __launch_bounds__(SCAN_B) void k_scan3(
    int* __restrict__ woff, const int* __restrict__ bscan, int* __restrict__ wpos) {
  const int i = blockIdx.x * SCAN_B + threadIdx.x;
  if (i < N) {
    int w = woff[i] + bscan[blockIdx.x];
    woff[i] = w;
    wpos[i] = w;
  }
}

// scatter src-ids into CSR; fused wsum[src] += 1/max(cnt[dst],1)
__global__ __launch_bounds__(256) void k_scatter(
    const int* __restrict__ ei, const int* __restrict__ cnt,
    int* __restrict__ wpos, int* __restrict__ adj, float* __restrict__ wsum) {
  int e = blockIdx.x * blockDim.x + threadIdx.x;
  if (e >= E) return;
  const int s = ei[e];
  const int d = ei[E + e];
  const int pos = atomicAdd(&wpos[d], 1);
  adj[pos] = s;
  const int c = cnt[d];
  atomicAdd(&wsum[s], 1.0f / (float)(c > 0 ? c : 1));
}

// one wave per dst node: coalesced adj read, broadcast-gather x rows,
// single non-atomic mean write. lane = feature.
__global__ __launch_bounds__(256) void k_gather(
    const float* __restrict__ x, const int* __restrict__ adj,
    const int* __restrict__ cnt, const int* __restrict__ woff,
    float* __restrict__ mean1) {
  const int lane = threadIdx.x & 63;
  const int n = (blockIdx.x * blockDim.x + threadIdx.x) >> 6;
  if (n >= N) return;
  const int deg = cnt[n];
  const int start = woff[n];
  float acc = 0.f;
  for (int base = 0; base < deg; base += 64) {
    const int rem = deg - base;
    const int mm = rem < 64 ? rem : 64;
    const int sl = (lane < mm) ? adj[start + base + lane] : 0;
    int i = 0;
    for (; i + 3 < mm; i += 4) {  // 4 loads in flight
      const int s0 = __shfl(sl, i, 64);
      const int s1 = __shfl(sl, i + 1, 64);
      const int s2 = __shfl(sl, i + 2, 64);
      const int s3 = __shfl(sl, i + 3, 64);
      const float v0 = x[(size_t)s0 * F + lane];
      const float v1 = x[(size_t)s1 * F + lane];
      const float v2 = x[(size_t)s2 * F + lane];
      const float v3 = x[(size_t)s3 * F + lane];
      acc += v0; acc += v1; acc += v2; acc += v3;
    }
    for (; i < mm; ++i) {
      const int s0 = __shfl(sl, i, 64);
      acc += x[(size_t)s0 * F + lane];
    }
  }
  const float winv = 1.0f / (float)(deg > 0 ? deg : 1);
  mean1[(size_t)n * F + lane] = acc * winv;
}

// Transposed layer-1: lane = hidden unit j. Weight rows in VGPRs (static
// indexing). Node loop broadcasts mean1/x rows as wave-uniform loads.
constexpr int NWG_NODE = 2500;
constexpr int NODES_PER_BLK = N / NWG_NODE;  // 20

__global__ __launch_bounds__(128) void k_node(
    const float* __restrict__ x, const float* __restrict__ mean1,
    const float* __restrict__ wsum,
    const float* __restrict__ W1l, const float* __restrict__ b1,
    const float* __restrict__ W1r,
    float* __restrict__ S_h, float* __restrict__ S_hw) {
  const int lane = threadIdx.x & 63;
  const int jhalf = threadIdx.x >> 6;
  const int j = jhalf * 64 + lane;

  float wl[F], wr[F];
  const float4* wlp = reinterpret_cast<const float4*>(W1l + j * F);
  const float4* wrp = reinterpret_cast<const float4*>(W1r + j * F);
  #pragma unroll
  for (int i = 0; i < F / 4; ++i) {
    float4 t = wlp[i];
    wl[4 * i] = t.x; wl[4 * i + 1] = t.y; wl[4 * i + 2] = t.z; wl[4 * i + 3] = t.w;
    float4 u = wrp[i];
    wr[4 * i] = u.x; wr[4 * i + 1] = u.y; wr[4 * i + 2] = u.z; wr[4 * i + 3] = u.w;
  }
  const float b1j = b1[j];

  float accS = 0.f, accW = 0.f;
  const int n0 = blockIdx.x * NODES_PER_BLK;
  const int n1 = n0 + NODES_PER_BLK;

  for (int n = n0; n < n1; ++n) {
    const float4* __restrict__ ar = reinterpret_cast<const float4*>(mean1 + (size_t)n * F);
    const float4* __restrict__ xr = reinterpret_cast<const float4*>(x + (size_t)n * F);
    float zl0 = 0.f, zl1 = 0.f, zr0 = 0.f, zr1 = 0.f;
    #pragma unroll
    for (int i = 0; i < F / 4; ++i) {
      float4 av = ar[i];  // wave-uniform -> broadcast load
      float4 xv = xr[i];
      zl0 = fmaf(wl[4 * i + 0], av.x, zl0);
      zl1 = fmaf(wl[4 * i + 1], av.y, zl1);
      zl0 = fmaf(wl[4 * i + 2], av.z, zl0);
      zl1 = fmaf(wl[4 * i + 3], av.w, zl1);
      zr0 = fmaf(wr[4 * i + 0], xv.x, zr0);
      zr1 = fmaf(wr[4 * i + 1], xv.y, zr1);
      zr0 = fmaf(wr[4 * i + 2], xv.z, zr0);
      zr1 = fmaf(wr[4 * i + 3], xv.w, zr1);
    }
    const float h = fmaxf((zl0 + zl1) + b1j + (zr0 + zr1), 0.0f);
    accS += h;
    accW = fmaf(wsum[n], h, accW);
  }

  atomicAdd(&S_h[j], accS);
  atomicAdd(&S_hw[j], accW);
}

__global__ __launch_bounds__(64) void k_final(
    const float* __restrict__ S_h, const float* __restrict__ S_hw,
    const float* __restrict__ W2l, const float* __restrict__ b2,
    const float* __restrict__ W2r, float* __restrict__ out) {
  const int j = threadIdx.x;
  if (j < O) {
    float acc = (float)N * b2[j];
    #pragma unroll 8
    for (int k = 0; k < H; ++k)
      acc += S_hw[k] * W2l[j * H + k] + S_h[k] * W2r[j * H + k];
    out[j] = acc;
  }
}

extern "C" void kernel_launch(void* const* d_in, const int* in_sizes, int n_in,
                              void* d_out, int out_size, void* d_ws, size_t ws_size,
                              hipStream_t stream) {
  const float* x   = (const float*)d_in[0];
  const int*   ei  = (const int*)d_in[1];
  const float* W1l = (const float*)d_in[2];
  const float* b1  = (const float*)d_in[3];
  const float* W1r = (const float*)d_in[4];
  const float* W2l = (const float*)d_in[5];
  const float* b2  = (const float*)d_in[6];
  const float* W2r = (const float*)d_in[7];
  float* out = (float*)d_out;
  float* ws  = (float*)d_ws;

  float* mean1 = ws + AGG_OFF;
  int*   cnt   = (int*)(ws + CNT_OFF);
  float* wsum  = ws + WSUM_OFF;
  int*   woff  = (int*)(ws + WOFF_OFF);
  int*   wpos  = (int*)(ws + WPOS_OFF);
  int*   adj   = (int*)(ws + ADJ_OFF);
  int*   bsum  = (int*)(ws + BSUM_OFF);
  int*   bscan = (int*)(ws + BSC_OFF);
  float* S_h   = ws + SH_OFF;
  float* S_hw  = ws + SHW_OFF;

  hipLaunchKernelGGL(k_zero, dim3((2 * N + 255) / 256), dim3(256), 0, stream, ws);
  hipLaunchKernelGGL(k_hist, dim3((E + 255) / 256), dim3(256), 0, stream, ei, cnt);
  hipLaunchKernelGGL(k_scan1, dim3(NBLK_SCAN), dim3(SCAN_B), 0, stream, cnt, woff, bsum);
  hipLaunchKernelGGL(k_scan2, dim3(1), dim3(SCAN_B), 0, stream, bsum, bscan);
  hipLaunchKernelGGL(k_scan3, dim3(NBLK_SCAN), dim3(SCAN_B), 0, stream, woff, bscan, wpos);
  hipLaunchKernelGGL(k_scatter, dim3((E + 255) / 256), dim3(256), 0, stream,
                     ei, cnt, wpos, adj, wsum);
  hipLaunchKernelGGL(k_gather, dim3((N + 3) / 4), dim3(256), 0, stream,
                     x, adj, cnt, woff, mean1);
  hipLaunchKernelGGL(k_node, dim3(NWG_NODE), dim3(128), 0, stream,
                     x, mean1, wsum, W1l, b1, W1r, S_h, S_hw);
  hipLaunchKernelGGL(k_final, dim3(1), dim3(64), 0, stream,
                     S_h, S_hw, W2l, b2, W2r, out);
}